// Round 8
// baseline (464.397 us; speedup 1.0000x reference)
//
#include <hip/hip_runtime.h>
#include <stdint.h>

// ExactTopKAttention: B=1, T=S=2048, H=16, E=64, topk=32, fp32.
//
// R20: coalesced-stage + shuffle-transpose exact recompute. R19 doubled
// occupancy (42->79%) for only -10us => not TLP-starved; remaining ~120us
// matches the R18-calibrated transaction-serialization rate applied to
// the recompute gather (each lane walks its own 4KB-apart K row: ~50-64
// cache lines per load instr, ~850 transactions/row x 32768 rows ~ 30M).
// Change: per 16-candidate chunk, lane l stages float4 #(l>>4)+4p of row
// (l&15) (contiguous 64B per row per instr => ~4 transactions/row), then
// every lane computes the BIT-IDENTICAL sequential e=0..63 fma chain for
// cand 16c+(l&15), pulling each float4 via __shfl (ds_bpermute) from the
// holding lane. Keep-predicate deposits into the same bitonic slots
// (slot0=lane, slot1=lane+64) as before; chain order, key packing, tie
// order unchanged => output bit-identical. Chunks with 16c >= n skipped
// (wave-uniform; n~34-66 typical => 3-5 chunks).
// Predicted: kernel2 222 -> 140-165us, VALU -> ~50%, VGPR ~50 (no spill).
//
// Structure (hardware-verified R14-R19):
//   prep: K -> Khi,Klo bf16 (RNE split) in fragment-ready chunks
//     [(h*128+g)*KSN+ks][lane] = lane's MFMA B-fragment bytes (R18).
//   main: 1024 thr = 16 waves; wave owns 128-s slice for scores, row wv
//     for threshold/recompute/output; scores = mfma 16x16 bf16 3-term
//     split (fp32 acc), |approx-exact| <= ~2e-3; per-j tile -> LDS u16
//     ord (col swizzle col^((row>>2)<<4)); bisection threshold; collect
//     at thr-3 bins (superset of exact top-32, cap 128); exact fp32
//     recompute (R12's e-chain); 128-wide bitonic on (ord32<<32 | ~idx);
//     softmax over 32; V gather.

#define T_DIM 2048
#define S_DIM 2048
#define H_DIM 16
#define E_DIM 64
#define K_TOP 32
#define TT 16        // t rows per block
#define CAND_CAP 128

typedef float f32x4 __attribute__((ext_vector_type(4)));
typedef short bf16x4 __attribute__((ext_vector_type(4)));
typedef short bf16x8 __attribute__((ext_vector_type(8)));

#if __has_builtin(__builtin_amdgcn_mfma_f32_16x16x16bf16_1k)
#define HAVE_MFMA16 1
#define MFMA16(a,b,c) __builtin_amdgcn_mfma_f32_16x16x16bf16_1k((a),(b),(c),0,0,0)
#define KSN 4        // fragment chunks per 16-s tile per buffer
#else
#define HAVE_MFMA16 0
#define KSN 2
#endif

__device__ __forceinline__ unsigned f2ord(float f) {
    unsigned b = __float_as_uint(f);
    return (b & 0x80000000u) ? ~b : (b | 0x80000000u);
}
__device__ __forceinline__ float ord2f(unsigned u) {
    unsigned b = (u & 0x80000000u) ? (u ^ 0x80000000u) : ~u;
    return __uint_as_float(b);
}
__device__ __forceinline__ unsigned short bf16rne(float f) {
    unsigned u = __float_as_uint(f);
    unsigned r = u + 0x7FFFu + ((u >> 16) & 1u);
    return (unsigned short)(r >> 16);
}
__device__ __forceinline__ float bf2f(unsigned short h) {
    return __uint_as_float(((unsigned)h) << 16);
}

// ---- kernel 1: K[s][h][e] fp32 -> fragment-ready Khi/Klo chunks ----
// (byte-identical to R18/R19, hardware-verified)
__global__ __launch_bounds__(256)
void prep_k(const float* __restrict__ Kg,
            unsigned short* __restrict__ Khi,
            unsigned short* __restrict__ Klo) {
    __shared__ float tile[64][65];
    const int tid = threadIdx.x;
    const int h   = blockIdx.x & (H_DIM - 1);
    const int b4  = blockIdx.x >> 4;           // 0..31, 64 s-rows each
    const int s0  = b4 * 64;
    #pragma unroll
    for (int p = 0; p < 16; p++) {             // coalesced: 64 floats/wave-row
        const int row = p * 4 + (tid >> 6);
        const int col = tid & 63;
        tile[row][col] = Kg[((size_t)(s0 + row) * H_DIM + h) * E_DIM + col];
    }
    __syncthreads();
    const int lane = tid & 63, wv = tid >> 6;  // 4 waves
    const int am = lane & 15, ag = lane >> 4;
    const int gp = wv;                         // wave wv owns s-tile wv (0..3)
#if HAVE_MFMA16
    #pragma unroll
    for (int ks = 0; ks < 4; ks++) {           // all 4 k-slices of this tile
        unsigned short hh[4], ll[4];
        #pragma unroll
        for (int i = 0; i < 4; i++) {
            float v = tile[gp * 16 + am][ks * 16 + ag * 4 + i];
            hh[i] = bf16rne(v);
            ll[i] = bf16rne(v - bf2f(hh[i]));
        }
        const size_t cb = ((((size_t)h * 128) + (b4 * 4 + gp)) * KSN + ks) * 64 + lane;
        uint2 ph, pl;
        ph.x = (unsigned)hh[0] | ((unsigned)hh[1] << 16);
        ph.y = (unsigned)hh[2] | ((unsigned)hh[3] << 16);
        pl.x = (unsigned)ll[0] | ((unsigned)ll[1] << 16);
        pl.y = (unsigned)ll[2] | ((unsigned)ll[3] << 16);
        *(uint2*)(Khi + cb * 4) = ph;          // 8B coalesced
        *(uint2*)(Klo + cb * 4) = pl;
    }
#else
    #pragma unroll
    for (int ks = 0; ks < 2; ks++) {           // both k-slices of this tile
        unsigned short hh[8], ll[8];
        #pragma unroll
        for (int i = 0; i < 8; i++) {
            float v = tile[gp * 16 + am][ks * 32 + ag * 8 + i];
            hh[i] = bf16rne(v);
            ll[i] = bf16rne(v - bf2f(hh[i]));
        }
        const size_t cb = ((((size_t)h * 128) + (b4 * 4 + gp)) * KSN + ks) * 64 + lane;
        uint4 ph, pl;
        ph.x = (unsigned)hh[0] | ((unsigned)hh[1] << 16);
        ph.y = (unsigned)hh[2] | ((unsigned)hh[3] << 16);
        ph.z = (unsigned)hh[4] | ((unsigned)hh[5] << 16);
        ph.w = (unsigned)hh[6] | ((unsigned)hh[7] << 16);
        pl.x = (unsigned)ll[0] | ((unsigned)ll[1] << 16);
        pl.y = (unsigned)ll[2] | ((unsigned)ll[3] << 16);
        pl.z = (unsigned)ll[4] | ((unsigned)ll[5] << 16);
        pl.w = (unsigned)ll[6] | ((unsigned)ll[7] << 16);
        *(uint4*)(Khi + cb * 8) = ph;          // 16B coalesced
        *(uint4*)(Klo + cb * 8) = pl;
    }
#endif
}

// ---- kernel 2: MFMA scores + exact top-32 + softmax + V ----
// 1024 thr = 16 waves; wave wv owns s-slice [wv*128, wv*128+128) for the
// score phase and row wv for threshold/recompute/output.
__global__ __launch_bounds__(1024, 8)
void topk_attn_kernel(const float* __restrict__ Qg,
                      const float* __restrict__ Kg,
                      const float* __restrict__ Vg,
                      const unsigned short* __restrict__ Khi,
                      const unsigned short* __restrict__ Klo,
                      float* __restrict__ Out) {
    __shared__ __align__(16) unsigned short sU[TT][S_DIM];    // 64 KB approx u16
    __shared__ unsigned short candI[TT][CAND_CAP];            // 4 KB
    __shared__ unsigned wcnt[TT];
    __shared__ unsigned thrA[TT];

    const int tid  = threadIdx.x;
    const int lane = tid & 63;
    const int wv   = tid >> 6;                 // wave 0..15
    const int bx   = blockIdx.x;
    const int h    = bx & (H_DIM - 1);         // same-h blocks -> same XCD
    const int t0   = (bx >> 4) * TT;
    if (tid < TT) wcnt[tid] = 0u;

    const int am = lane & 15;                  // A row (t) / B col (s) index
    const int ag = lane >> 4;                  // k-group 0..3

    // ---- A fragments: Q rows t0..t0+15, bf16 3-way split, registers ----
    const float* Qrow = Qg + ((size_t)(t0 + am) * H_DIM + h) * E_DIM;
#if HAVE_MFMA16
    bf16x4 Ahi[4], Alo[4];
    #pragma unroll
    for (int ks = 0; ks < 4; ks++) {
        #pragma unroll
        for (int i = 0; i < 4; i++) {
            float q = Qrow[ks * 16 + ag * 4 + i];
            unsigned short hi = bf16rne(q);
            Ahi[ks][i] = (short)hi;
            Alo[ks][i] = (short)bf16rne(q - bf2f(hi));
        }
    }
#else
    bf16x8 Ahi[2], Alo[2];
    #pragma unroll
    for (int ks = 0; ks < 2; ks++) {
        #pragma unroll
        for (int i = 0; i < 8; i++) {
            float q = Qrow[ks * 32 + (ag << 3) + i];
            unsigned short hi = bf16rne(q);
            Ahi[ks][i] = (short)hi;
            Alo[ks][i] = (short)bf16rne(q - bf2f(hi));
        }
    }
#endif

    // ---- MFMA: 8 tiles per wave; per-j compute -> convert -> LDS ----
    const int sw = wv * 128;
    #pragma unroll 2
    for (int j = 0; j < 8; j++) {
        const int g = wv * 8 + j;              // s-tile index within head
        f32x4 aHH = (f32x4)(0.f), aHL = (f32x4)(0.f), aLH = (f32x4)(0.f);
#if HAVE_MFMA16
        #pragma unroll
        for (int ks = 0; ks < 4; ks++) {
            const size_t cb = (((size_t)h * 128 + g) * KSN + ks) * 64 + lane;
            bf16x4 bh = *(const bf16x4*)(Khi + cb * 4);   // coalesced 512B
            bf16x4 bl = *(const bf16x4*)(Klo + cb * 4);
            aHH = MFMA16(Ahi[ks], bh, aHH);
            aHL = MFMA16(Ahi[ks], bl, aHL);
            aLH = MFMA16(Alo[ks], bh, aLH);
        }
#else
        #pragma unroll
        for (int ks = 0; ks < 2; ks++) {
            const size_t cb = (((size_t)h * 128 + g) * KSN + ks) * 64 + lane;
            bf16x8 bh = *(const bf16x8*)(Khi + cb * 8);   // coalesced 1KB
            bf16x8 bl = *(const bf16x8*)(Klo + cb * 8);
            aHH = __builtin_amdgcn_mfma_f32_16x16x32_bf16(Ahi[ks], bh, aHH, 0, 0, 0);
            aHL = __builtin_amdgcn_mfma_f32_16x16x32_bf16(Ahi[ks], bl, aHL, 0, 0, 0);
            aLH = __builtin_amdgcn_mfma_f32_16x16x32_bf16(Alo[ks], bh, aLH, 0, 0, 0);
        }
#endif
        f32x4 acc = (aHH + aHL) + aLH;
        // C/D layout: lane holds rows m = ag*4+i, col s = sw + 16j + am.
        const int cswz = (sw + j * 16 + am) ^ (ag << 4);
        #pragma unroll
        for (int i = 0; i < 4; i++)
            sU[ag * 4 + i][cswz] = (unsigned short)(f2ord(acc[i]) >> 16);
    }
    __syncthreads();

    // ---- threshold: wave wv owns row wv; LDS-direct count16 ----
    {
        const unsigned* rowp = (const unsigned*)(&sU[wv][0]);
        auto count16 = [&](unsigned t) -> int {    // wave-uniform result
            int c = 0;
            #pragma unroll
            for (int jj = 0; jj < 16; jj++) {
                const unsigned w = rowp[jj * 64 + lane];
                c += __popcll(__ballot((w & 0xFFFFu) >= t));
                c += __popcll(__ballot((w >> 16) >= t));
            }
            return c;
        };
        unsigned thr = 0xC180u;                    // f2ord(16.0f)>>16 (2sigma)
        int c = count16(thr);
        if (c < K_TOP || c > 64) {
            unsigned lo = (c >= K_TOP) ? thr : 0u;
            unsigned hi = (c >= K_TOP) ? 0x10000u : thr;
            bool found = false;
            while (!found && (hi - lo > 1u)) {
                unsigned mid = lo + ((hi - lo) >> 1);
                int cm = count16(mid);
                if (cm >= K_TOP && cm <= 64) { thr = mid; found = true; }
                else if (cm >= K_TOP) lo = mid;
                else hi = mid;
            }
            if (!found) thr = lo;                  // count(lo) >= 32 invariant
        }
        // collect threshold: -3 bins (>= 2*eps margin) => superset of the
        // exact top-32; count(thr)>=32 guarantees >=32 candidates.
        if (lane == 0) thrA[wv] = (thr > 3u) ? (thr - 3u) : 1u;
    }
    __syncthreads();

    // ---- collect: wave scans its 128-col slice (64 u32) of every row ----
    #pragma unroll 1
    for (int r = 0; r < TT; r++) {
        const unsigned tr = thrA[r];
        const unsigned sz = ((unsigned)(r >> 2) & 3u) << 4;
        const int c32 = (sw >> 1) + lane;
        const unsigned w = ((const unsigned*)(&sU[r][0]))[c32];
        if ((w & 0xFFFFu) >= tr) {
            unsigned p = atomicAdd(&wcnt[r], 1u);
            if (p < CAND_CAP) candI[r][p] = (unsigned short)((unsigned)(2 * c32) ^ sz);
        }
        if ((w >> 16) >= tr) {
            unsigned p = atomicAdd(&wcnt[r], 1u);
            if (p < CAND_CAP) candI[r][p] = (unsigned short)((unsigned)(2 * c32 + 1) ^ sz);
        }
    }
    __syncthreads();

    // ---- wave wv: exact recompute (coalesced stage + shuffle transpose),
    //      128-bitonic, softmax, V gather for row wv ----
    {
        const int t = t0 + wv;
        const unsigned nw = wcnt[wv];
        const int n = (nw > CAND_CAP) ? CAND_CAP : (int)nw;
        const float* Qr = Qg + ((size_t)t * H_DIM + h) * E_DIM;  // uniform

        unsigned long long key0 = 0ull, key1 = 0ull;
        // chunks of 16 candidates; lane l computes cand 16c + (l&15)
        // (4-way redundant); keep lanes deposit into slot0/slot1.
        #pragma unroll 1
        for (int c = 0; c < 8; c++) {
            if (c * 16 >= n) break;            // wave-uniform
            const unsigned cidx = (unsigned)(c * 16) + (unsigned)(lane & 15);
            const int sc = (cidx < (unsigned)n) ? (int)candI[wv][cidx] : 0;
            const float* kp = Kg + ((size_t)sc * H_DIM + h) * E_DIM;
            // stage: float4 #((lane>>4)+4p) -> contiguous 64B per row/instr
            float4 fp[4];
            #pragma unroll
            for (int p = 0; p < 4; p++)
                fp[p] = *(const float4*)(kp + ((lane >> 4) + 4 * p) * 4);
            // exact fp32 chain, e = 0..63 sequential (== R12's rounding);
            // float4 #e4 (e4 = 4p+m) held by lane (l&15)+(m<<4) in fp[p].
            float a = 0.f;
            #pragma unroll
            for (int p = 0; p < 4; p++) {
                #pragma unroll
                for (int m = 0; m < 4; m++) {
                    const int src = (lane & 15) + (m << 4);
                    float4 kx;
                    kx.x = __shfl(fp[p].x, src);
                    kx.y = __shfl(fp[p].y, src);
                    kx.z = __shfl(fp[p].z, src);
                    kx.w = __shfl(fp[p].w, src);
                    const float4 q4 = *(const float4*)(Qr + (p * 4 + m) * 4);
                    a = fmaf(q4.x, kx.x, a);
                    a = fmaf(q4.y, kx.y, a);
                    a = fmaf(q4.z, kx.z, a);
                    a = fmaf(q4.w, kx.w, a);
                }
            }
            const bool keep = (c < 4) ? ((lane >> 4) == c) : ((lane >> 4) == c - 4);
            if (keep && cidx < (unsigned)n) {
                unsigned long long kk =
                    (((unsigned long long)f2ord(a)) << 32) | (unsigned)(~sc);
                if (c < 4) key0 = kk; else key1 = kk;
            }
        }

        // bitonic-128 desc, 2 keys/lane (seq pos: slot0 = lane, slot1 = lane+64)
        #pragma unroll
        for (int k = 2; k <= 128; k <<= 1) {
            #pragma unroll
            for (int j = k >> 1; j > 0; j >>= 1) {
                if (j == 64) {                 // only at k=128: in-lane swap
                    unsigned long long mx = key0 > key1 ? key0 : key1;
                    unsigned long long mn = key0 > key1 ? key1 : key0;
                    key0 = mx; key1 = mn;
                } else {
                    unsigned long long o0 = __shfl_xor(key0, j);
                    unsigned long long o1 = __shfl_xor(key1, j);
                    const bool lj  = (lane & j) == 0;
                    const bool tm0 = lj ^ ((lane & k) != 0);
                    const bool tm1 = lj ^ (((lane + 64) & k) != 0);
                    key0 = (tm0 == (key0 > o0)) ? key0 : o0;
                    key1 = (tm1 == (key1 > o1)) ? key1 : o1;
                }
            }
        }

        // decode + softmax + V gather (== R12, on slot0)
        float val  = ord2f((unsigned)(key0 >> 32)) * 0.125f;
        int   sidx = (int)(~(unsigned)key0);
        float m = __shfl(val, 0);
        float w = (lane < K_TOP) ? expf(val - m) : 0.f;
        float Z = w;
        #pragma unroll
        for (int d = 32; d > 0; d >>= 1) Z += __shfl_xor(Z, d);
        float pr = w / Z;

        const float* Vb = Vg + (size_t)h * E_DIM;
        float o = 0.f;
        #pragma unroll
        for (int i2 = 0; i2 < K_TOP; i2++) {
            float pi = __shfl(pr, i2);
            int   s2 = __shfl(sidx, i2);
            o = fmaf(pi, Vb[(size_t)s2 * (H_DIM * E_DIM) + lane], o);
        }
        Out[((size_t)t * H_DIM + h) * E_DIM + lane] = o;
    }
}

extern "C" void kernel_launch(void* const* d_in, const int* in_sizes, int n_in,
                              void* d_out, int out_size, void* d_ws, size_t ws_size,
                              hipStream_t stream) {
    const float* Q = (const float*)d_in[0];
    const float* K = (const float*)d_in[1];
    const float* V = (const float*)d_in[2];
    float* O = (float*)d_out;
    unsigned short* Khi = (unsigned short*)d_ws;               // 4 MB
    unsigned short* Klo = Khi + (size_t)S_DIM * H_DIM * E_DIM; // 4 MB
    (void)in_sizes; (void)n_in; (void)out_size; (void)ws_size;
    prep_k<<<dim3(H_DIM * (S_DIM / 64)), dim3(256), 0, stream>>>(K, Khi, Klo);
    topk_attn_kernel<<<dim3((T_DIM / TT) * H_DIM), dim3(1024), 0, stream>>>(Q, K, V, Khi, Klo, O);
}